// Round 3
// baseline (53.977 us; speedup 1.0000x reference)
//
#include <hip/hip_runtime.h>

#define NB 16
#define NK 256
#define ND 256
#define NH 128
#define NM (NB * NK)  // 4096 rows total

// Workspace layout:
//   GT : [256 n][4096 m] f32, 4 MB.  Rows 0..127 = A^T = (x@W1a)^T,
//        rows 128..255 = C^T = (x@W1b + b1)^T.
//   mh : [4096 m][128 h] f32, 2 MB.

// ---------------------------------------------------------------------------
// k1: G^T = ([x@W1a ; x@W1b + b1])^T.
// Block: 256 thr = 4 waves. Wave = 64 m-rows (lane=m) x 8 n-cols.
// x-tile staged in LDS as Xs^T[k][m] with XOR-swizzled columns (conflict-free
// stage-write AND read). W1 n-slices are wave-uniform -> scalar loads; the
// inner loop is v_fma(v, s, v): 8 FMA per 1 LDS b32 read.
// Grid (64 m-tiles, 8 n-groups of 32) = 512 blocks, 2 blocks/CU (128KB LDS).
// ---------------------------------------------------------------------------
__global__ __launch_bounds__(256) void k1_gemm_t(
    const float* __restrict__ x, const float* __restrict__ W1,
    const float* __restrict__ b1, float* __restrict__ GT)
{
  __shared__ float Xs[NK * 64];  // Xs^T[k][m] at Xs[k*64 + (m ^ (k>>2))]

  const int tid  = threadIdx.x;
  const int lane = tid & 63;
  const int mt   = blockIdx.x;   // 0..63
  const int bn   = blockIdx.y;   // 0..7
  const int m0   = mt * 64;

  // stage x-tile [64 m][256 k]: 16 rounds, coalesced float4 loads,
  // swizzled conflict-free ds_write_b32 x4.
#pragma unroll
  for (int r = 0; r < 16; ++r) {
    const int q  = r * 256 + tid;  // float4 id
    const int m  = q >> 6;         // 0..63 (wave-uniform per round)
    const int kq = q & 63;         // = lane
    const float4 v = *(const float4*)&x[(size_t)(m0 + m) * ND + kq * 4];
    const int col = m ^ kq;
    Xs[(kq * 4 + 0) * 64 + col] = v.x;
    Xs[(kq * 4 + 1) * 64 + col] = v.y;
    Xs[(kq * 4 + 2) * 64 + col] = v.z;
    Xs[(kq * 4 + 3) * 64 + col] = v.w;
  }
  __syncthreads();

  const int wu = __builtin_amdgcn_readfirstlane(tid >> 6);  // 0..3, uniform
  const int n0 = bn * 32 + wu * 8;                          // global n base
  const bool isC = n0 >= 128;
  // W1c[k][n] = (n<128) ? W1[k*128+n] : W1[(256+k)*128 + (n-128)]
  const float* __restrict__ wb = W1 + (isC ? (n0 + 32640) : n0);

  float acc[8] = {};
#pragma unroll 4
  for (int k = 0; k < NK; ++k) {
    const float xv = Xs[k * 64 + (lane ^ (k >> 2))];
    const float* __restrict__ wk = wb + k * NH;  // wave-uniform -> s_load
#pragma unroll
    for (int i = 0; i < 8; ++i) acc[i] = fmaf(xv, wk[i], acc[i]);
  }

#pragma unroll
  for (int i = 0; i < 8; ++i) {
    float v = acc[i];
    if (isC) v += b1[n0 - 128 + i];
    GT[(size_t)(n0 + i) * NM + m0 + lane] = v;  // coalesced 256B wave-store
  }
}

// ---------------------------------------------------------------------------
// k2a: pairwise-mean via exact identity
//   mh[m,h] = (256*a[m,h] + sumC[b,h] + sum_k2 |a[m,h]+c[b,k2,h]|) / 512
// Wave = (b, h, 64 k1-rows): lane holds a (one coalesced load from A^T);
// the c-row C^T[h][b*256..] is WAVE-UNIFORM -> scalar loads; hot loop is
// 2 VALU per element, zero LDS. Block = 8 waves = 8 h values; epilogue
// transposes 64x8 through LDS -> coalesced mh[m][h] stores.
// Grid (16 b, 4 k1-tiles, 16 h-blocks) = 1024 blocks, 32 waves/CU.
// ---------------------------------------------------------------------------
__global__ __launch_bounds__(512) void k2a_pair(
    const float* __restrict__ GT, float* __restrict__ mh)
{
  __shared__ float tl[64][9];  // padded: conflict-free column writes

  const int tid  = threadIdx.x;
  const int lane = tid & 63;
  const int wu   = __builtin_amdgcn_readfirstlane(tid >> 6);  // 0..7
  const int b    = blockIdx.x;   // 0..15
  const int kt   = blockIdx.y;   // 0..3
  const int hb   = blockIdx.z;   // 0..15
  const int h    = hb * 8 + wu;
  const int m0   = b * NK + kt * 64;

  const float a = GT[(size_t)h * NM + m0 + lane];
  const float* __restrict__ cb = GT + (size_t)(128 + h) * NM + b * NK;  // uniform

  // sumC: 4 vector loads + butterfly reduce (all 64 lanes end with the sum)
  float sumC = cb[lane] + cb[64 + lane] + cb[128 + lane] + cb[192 + lane];
#pragma unroll
  for (int off = 32; off >= 1; off >>= 1) sumC += __shfl_xor(sumC, off, 64);

  float ab = 0.f;
#pragma unroll 8
  for (int k2 = 0; k2 < NK; ++k2) {
    const float c = cb[k2];      // uniform -> s_load
    ab += fabsf(a + c);          // 2 VALU
  }

  tl[lane][wu] = (256.f * a + sumC + ab) * (1.f / 512.f);
  __syncthreads();

  if (tid < 64) {
    float4 v0 = make_float4(tl[tid][0], tl[tid][1], tl[tid][2], tl[tid][3]);
    float4 v1 = make_float4(tl[tid][4], tl[tid][5], tl[tid][6], tl[tid][7]);
    float* dst = mh + (size_t)(m0 + tid) * NH + hb * 8;
    *(float4*)dst = v0;
    *(float4*)(dst + 4) = v1;
  }
}

// ---------------------------------------------------------------------------
// k2b: out[m][d] = mh[m,:] @ W2[:,d] + b2[d] + x[m][d].
// Thread = d (256 threads), block = 16 m-rows. mh rows are BLOCK-uniform
// (blockIdx-derived addresses only) -> guaranteed s_loads; W2 rows coalesced.
// Grid 256 blocks.
// ---------------------------------------------------------------------------
__global__ __launch_bounds__(256) void k2b_gemm2(
    const float* __restrict__ mh, const float* __restrict__ W2,
    const float* __restrict__ b2, const float* __restrict__ x,
    float* __restrict__ out)
{
  const int d  = threadIdx.x;
  const int m0 = blockIdx.x * 16;

  float acc[16] = {};
  for (int hc = 0; hc < NH; hc += 4) {
    const float w0 = W2[(size_t)(hc + 0) * ND + d];
    const float w1 = W2[(size_t)(hc + 1) * ND + d];
    const float w2 = W2[(size_t)(hc + 2) * ND + d];
    const float w3 = W2[(size_t)(hc + 3) * ND + d];
#pragma unroll
    for (int i = 0; i < 16; ++i) {
      const float* __restrict__ mb = mh + (size_t)(m0 + i) * NH + hc;  // uniform
      acc[i] = fmaf(mb[0], w0, acc[i]);
      acc[i] = fmaf(mb[1], w1, acc[i]);
      acc[i] = fmaf(mb[2], w2, acc[i]);
      acc[i] = fmaf(mb[3], w3, acc[i]);
    }
  }

  const float bias = b2[d];
#pragma unroll
  for (int i = 0; i < 16; ++i) {
    const size_t o = (size_t)(m0 + i) * ND + d;
    out[o] = acc[i] + bias + x[o];
  }
}

extern "C" void kernel_launch(void* const* d_in, const int* in_sizes, int n_in,
                              void* d_out, int out_size, void* d_ws, size_t ws_size,
                              hipStream_t stream) {
  const float* x  = (const float*)d_in[0];
  const float* W1 = (const float*)d_in[1];
  const float* b1 = (const float*)d_in[2];
  const float* W2 = (const float*)d_in[3];
  const float* b2 = (const float*)d_in[4];
  float* out = (float*)d_out;

  float* GT = (float*)d_ws;                 // 256 x 4096 f32 = 4 MB
  float* mh = GT + (size_t)256 * NM;        // 4096 x 128 f32 = 2 MB

  k1_gemm_t<<<dim3(64, 8), 256, 0, stream>>>(x, W1, b1, GT);
  k2a_pair<<<dim3(16, 4, 16), 512, 0, stream>>>(GT, mh);
  k2b_gemm2<<<256, 256, 0, stream>>>(mh, W2, b2, x, out);
}

// Round 4
// 47.969 us; speedup vs baseline: 1.1252x; 1.1252x over previous
//
#include <hip/hip_runtime.h>

#define NB 16
#define NK 256
#define ND 256
#define NH 128
#define NM (NB * NK)  // 4096 rows total

// Workspace: xT [256 k][4096 m] (4 MB) | GT [256 n][4096 m] (4 MB) | mh [4096][128] (2 MB)
// GT rows 0..127 = A^T = (x@W1a)^T ; rows 128..255 = C^T = (x@W1b + b1)^T.

// ---------------------------------------------------------------------------
// kT: xT[k][m] = x[m][k].  64x64 tiles through padded LDS, all global
// accesses coalesced. Grid (64, 4), 256 thr.
// ---------------------------------------------------------------------------
__global__ __launch_bounds__(256) void kT_transpose(
    const float* __restrict__ x, float* __restrict__ xT)
{
  __shared__ float Ls[64][65];
  const int t   = threadIdx.x;
  const int m0  = blockIdx.x * 64;
  const int k0  = blockIdx.y * 64;
  const int r16 = t >> 4;      // 0..15
  const int c4  = t & 15;      // 0..15

#pragma unroll
  for (int j = 0; j < 4; ++j) {
    const int row = r16 + j * 16;  // m-local
    float4 v = *(const float4*)&x[(size_t)(m0 + row) * ND + k0 + c4 * 4];
    Ls[c4 * 4 + 0][row] = v.x;
    Ls[c4 * 4 + 1][row] = v.y;
    Ls[c4 * 4 + 2][row] = v.z;
    Ls[c4 * 4 + 3][row] = v.w;
  }
  __syncthreads();

#pragma unroll
  for (int j = 0; j < 4; ++j) {
    const int kl = r16 + j * 16;  // k-local
    float4 v = make_float4(Ls[kl][c4 * 4 + 0], Ls[kl][c4 * 4 + 1],
                           Ls[kl][c4 * 4 + 2], Ls[kl][c4 * 4 + 3]);
    *(float4*)&xT[(size_t)(k0 + kl) * NM + m0 + c4 * 4] = v;
  }
}

// ---------------------------------------------------------------------------
// k1: GT = ([x@W1a ; x@W1b + b1])^T, computed as GT[n][m].
// NO LDS in hot loop. Per k: 1 coalesced global load of xT[k][m0+lane]
// (vmcnt) + s_load_dwordx8 of the wave-uniform W1 slice (lgkmcnt) + 8 FMA.
// Independent counters -> both prefetch. Grid (64 m-tiles, 8 n-groups),
// 256 thr, no LDS -> 16 waves/CU.
// ---------------------------------------------------------------------------
__global__ __launch_bounds__(256) void k1_gemm_t(
    const float* __restrict__ xT, const float* __restrict__ W1,
    const float* __restrict__ b1, float* __restrict__ GT)
{
  const int tid  = threadIdx.x;
  const int lane = tid & 63;
  const int wu   = __builtin_amdgcn_readfirstlane(tid >> 6);  // 0..3 uniform
  const int m0   = blockIdx.x * 64;
  const int n0   = blockIdx.y * 32 + wu * 8;   // 0..248
  const bool isC = n0 >= 128;
  // Wc[k][n]: n<128 -> W1[k*128+n]; n>=128 -> W1[(256+k)*128 + (n-128)]
  const float* __restrict__ wb = W1 + (isC ? (256 * NH + n0 - 128) : n0);
  const float* __restrict__ xp = xT + m0 + lane;

  float acc[8] = {};
#pragma unroll 8
  for (int k = 0; k < NK; ++k) {
    const float xv = xp[(size_t)k * NM];         // coalesced vload
    const float* __restrict__ wk = wb + (size_t)k * NH;  // uniform -> s_load
#pragma unroll
    for (int i = 0; i < 8; ++i) acc[i] = fmaf(xv, wk[i], acc[i]);
  }

#pragma unroll
  for (int i = 0; i < 8; ++i) {
    float v = acc[i];
    if (isC) v += b1[n0 - 128 + i];
    GT[(size_t)(n0 + i) * NM + m0 + lane] = v;   // coalesced 256B store
  }
}

// ---------------------------------------------------------------------------
// k2a: mh[m,h] = (256*a[m,h] + sumC[b,h] + sum_k2 |a[m,h]+c[b,k2,h]|) / 512
// Wave = (b, h, 64 m-rows): a per-lane (1 coalesced load), c-row wave-uniform
// -> s_loads; hot loop 2 VALU/element, zero LDS. Block 512 thr = 8 h values;
// epilogue transposes 64x8 through LDS. Grid (16,4,16), 4 blocks/CU = 32 w/CU.
// ---------------------------------------------------------------------------
__global__ __launch_bounds__(512) void k2a_pair(
    const float* __restrict__ GT, float* __restrict__ mh)
{
  __shared__ float tl[64][9];

  const int tid  = threadIdx.x;
  const int lane = tid & 63;
  const int wu   = __builtin_amdgcn_readfirstlane(tid >> 6);  // 0..7
  const int b    = blockIdx.x;
  const int kt   = blockIdx.y;
  const int hb   = blockIdx.z;
  const int h    = hb * 8 + wu;
  const int m0   = b * NK + kt * 64;

  const float a = GT[(size_t)h * NM + m0 + lane];
  const float* __restrict__ cb = GT + (size_t)(128 + h) * NM + b * NK;  // uniform

  float sumC = cb[lane] + cb[64 + lane] + cb[128 + lane] + cb[192 + lane];
#pragma unroll
  for (int off = 32; off >= 1; off >>= 1) sumC += __shfl_xor(sumC, off, 64);

  float ab = 0.f;
#pragma unroll 8
  for (int k2 = 0; k2 < NK; ++k2) {
    const float c = cb[k2];   // uniform -> s_load (batches to dwordx8)
    ab += fabsf(a + c);
  }

  tl[lane][wu] = (256.f * a + sumC + ab) * (1.f / 512.f);
  __syncthreads();

  if (tid < 64) {
    float4 v0 = make_float4(tl[tid][0], tl[tid][1], tl[tid][2], tl[tid][3]);
    float4 v1 = make_float4(tl[tid][4], tl[tid][5], tl[tid][6], tl[tid][7]);
    float* dst = mh + (size_t)(m0 + tid) * NH + hb * 8;
    *(float4*)dst = v0;
    *(float4*)(dst + 4) = v1;
  }
}

// ---------------------------------------------------------------------------
// k2b: out[m][d] = mh[m,:] @ W2[:,d] + b2[d] + x[m][d].
// Thread = d; block = 8 m-rows -> grid 512 (2 blocks/CU, 8 waves/CU).
// Per 8-h chunk: 8 uniform s_load_dwordx8 (mh rows) + 8 coalesced W2-row
// vloads + 64 FMA. Stores + residual coalesced.
// ---------------------------------------------------------------------------
__global__ __launch_bounds__(256) void k2b_gemm2(
    const float* __restrict__ mh, const float* __restrict__ W2,
    const float* __restrict__ b2, const float* __restrict__ x,
    float* __restrict__ out)
{
  const int d  = threadIdx.x;
  const int m0 = blockIdx.x * 8;

  float acc[8] = {};
  for (int hc = 0; hc < NH; hc += 8) {
    float w[8];
#pragma unroll
    for (int j = 0; j < 8; ++j) w[j] = W2[(size_t)(hc + j) * ND + d];
#pragma unroll
    for (int i = 0; i < 8; ++i) {
      const float* __restrict__ mb = mh + (size_t)(m0 + i) * NH + hc;  // uniform
#pragma unroll
      for (int j = 0; j < 8; ++j) acc[i] = fmaf(mb[j], w[j], acc[i]);
    }
  }

  const float bias = b2[d];
#pragma unroll
  for (int i = 0; i < 8; ++i) {
    const size_t o = (size_t)(m0 + i) * ND + d;
    out[o] = acc[i] + bias + x[o];
  }
}

extern "C" void kernel_launch(void* const* d_in, const int* in_sizes, int n_in,
                              void* d_out, int out_size, void* d_ws, size_t ws_size,
                              hipStream_t stream) {
  const float* x  = (const float*)d_in[0];
  const float* W1 = (const float*)d_in[1];
  const float* b1 = (const float*)d_in[2];
  const float* W2 = (const float*)d_in[3];
  const float* b2 = (const float*)d_in[4];
  float* out = (float*)d_out;

  float* xT = (float*)d_ws;                  // 256 x 4096 = 4 MB
  float* GT = xT + (size_t)256 * NM;         // 256 x 4096 = 4 MB
  float* mh = GT + (size_t)256 * NM;         // 4096 x 128 = 2 MB

  kT_transpose<<<dim3(64, 4), 256, 0, stream>>>(x, xT);
  k1_gemm_t<<<dim3(64, 8), 256, 0, stream>>>(xT, W1, b1, GT);
  k2a_pair<<<dim3(16, 4, 16), 512, 0, stream>>>(GT, mh);
  k2b_gemm2<<<512, 256, 0, stream>>>(mh, W2, b2, x, out);
}

// Round 5
// 33.134 us; speedup vs baseline: 1.6290x; 1.4477x over previous
//
#include <hip/hip_runtime.h>

#define NM 4096   // B*K rows
#define NKI 256   // inner k of GEMM1 (= D)
#define NH 128
#define ND 256

typedef __attribute__((ext_vector_type(8))) short bf16x8;
typedef __attribute__((ext_vector_type(4))) float f32x4;

__device__ __forceinline__ unsigned short f2bf(float f) {
  unsigned u = __float_as_uint(f);
  u += 0x7FFFu + ((u >> 16) & 1u);   // RNE
  return (unsigned short)(u >> 16);
}

// ---------------------------------------------------------------------------
// kCast: W1T[n][k] bf16 (n<128: A-half, n>=128: B-half) ; W2T[d][h] bf16.
// ---------------------------------------------------------------------------
__global__ __launch_bounds__(256) void kCast(
    const float* __restrict__ W1, const float* __restrict__ W2,
    unsigned short* __restrict__ W1T, unsigned short* __restrict__ W2T)
{
  int id = blockIdx.x * 256 + threadIdx.x;
  if (id < 65536) {                       // 256 n x 256 k
    int n = id & 255, k = id >> 8;
    float v = (n < 128) ? W1[k * 128 + n] : W1[(256 + k) * 128 + (n - 128)];
    W1T[n * 256 + k] = f2bf(v);
  } else {
    int id2 = id - 65536;                 // 256 d x 128 h
    int d = id2 & 255, h = id2 >> 8;
    W2T[d * 128 + h] = f2bf(W2[h * 256 + d]);
  }
}

// ---------------------------------------------------------------------------
// k1: GT[n][m] f32 = rows n<128: (x@W1a)^T ; n>=128: (x@W1b+b1)^T.
// MFMA 16x16x32 bf16: D = mfma(Afrag, Bfrag): row <- A's 16-dim (n),
// col <- B's 16-dim (m). A-frags (W1T rows) hoisted in regs; B (x tile)
// cast to bf16 into swizzled LDS. Block 256 thr: 32 m x 64 n. Grid (128,4).
// ---------------------------------------------------------------------------
__global__ __launch_bounds__(256) void k1_mfma(
    const float* __restrict__ x, const unsigned short* __restrict__ W1T,
    const float* __restrict__ b1, float* __restrict__ GT)
{
  __shared__ unsigned short xs[32 * 256];  // [m][k] bf16, 8B-unit XOR swizzle

  const int tid = threadIdx.x, lane = tid & 63, wu = tid >> 6;  // wu 0..3
  const int m0 = blockIdx.x * 32;
  const int n0 = blockIdx.y * 64;
  const int fr = lane & 15, fq = lane >> 4;

  // A-frags: W1T[n0+wu*16+fr][kc*32 + fq*8 .. +8], 8 chunks (global, L2-hot)
  bf16x8 afr[8];
  const unsigned short* ap = W1T + (size_t)(n0 + wu * 16 + fr) * 256 + fq * 8;
#pragma unroll
  for (int c = 0; c < 8; ++c) afr[c] = *(const bf16x8*)(ap + c * 32);

  // stage x tile [32 m][256 k] -> bf16 LDS; 8B unit u, phys = u^((row&7)<<1)
#pragma unroll
  for (int r = 0; r < 8; ++r) {
    int idx = r * 256 + tid;
    int row = idx >> 6, u = idx & 63;
    float4 v = *(const float4*)&x[(size_t)(m0 + row) * NKI + u * 4];
    ushort4 hv = make_ushort4(f2bf(v.x), f2bf(v.y), f2bf(v.z), f2bf(v.w));
    int pu = u ^ ((row & 7) << 1);
    *(ushort4*)&xs[row * 256 + pu * 4] = hv;
  }
  __syncthreads();

#pragma unroll
  for (int ms = 0; ms < 2; ++ms) {
    f32x4 acc = {0.f, 0.f, 0.f, 0.f};
    const int mrow = ms * 16 + fr;
    const int xsw = (mrow & 7) << 1;
#pragma unroll
    for (int c = 0; c < 8; ++c) {
      int pu = (c * 8 + fq * 2) ^ xsw;
      bf16x8 bfr = *(const bf16x8*)&xs[mrow * 256 + pu * 4];
      acc = __builtin_amdgcn_mfma_f32_16x16x32_bf16(afr[c], bfr, acc, 0, 0, 0);
    }
    const int nb = n0 + wu * 16 + fq * 4;
    const int m = m0 + ms * 16 + fr;
#pragma unroll
    for (int g = 0; g < 4; ++g) {
      float v = acc[g];
      const int nn = nb + g;
      if (nn >= 128) v += b1[nn - 128];
      GT[(size_t)nn * NM + m] = v;
    }
  }
}

// ---------------------------------------------------------------------------
// k2a: mh[m,h] = (256*a + sumC + sum_k2 |a+c|)/512  (exact relu-sum identity)
// Block 512 thr = 8 waves = 8 h; covers (b, m-tile 128). c-row in LDS, hot
// loop reads it as BROADCAST ds_read_b128 (uniform addr) — 1 LDS instr per
// 8 pairs/thread. R=2 rows/thread. Output mhb bf16 via LDS transpose.
// Grid (16 b, 2 m-tiles, 16 h-chunks) = 512 blocks -> 16 waves/CU.
// ---------------------------------------------------------------------------
__global__ __launch_bounds__(512) void k2a_pair(
    const float* __restrict__ GT, unsigned short* __restrict__ mhb)
{
  __shared__ float Cs[8][256];
  __shared__ unsigned short tl[128][8];

  const int tid = threadIdx.x, lane = tid & 63, wu = tid >> 6;  // wu 0..7
  const int b = blockIdx.x, mt = blockIdx.y, hc = blockIdx.z;
  const int h0 = hc * 8, r0 = mt * 128;

  // stage 8 c-rows (8KB): 512 threads x 1 float4, coalesced
  {
    int j = tid >> 6, c4 = tid & 63;
    *(float4*)&Cs[j][c4 * 4] =
        *(const float4*)&GT[(size_t)(128 + h0 + j) * NM + b * 256 + c4 * 4];
  }
  const int h = h0 + wu;
  const float* __restrict__ arow = GT + (size_t)h * NM + b * 256 + r0;
  const float av0 = arow[lane];
  const float av1 = arow[64 + lane];
  __syncthreads();

  // sumC for this h: 4 floats/lane + butterfly
  float4 s4 = *(const float4*)&Cs[wu][lane * 4];
  float sumC = (s4.x + s4.y) + (s4.z + s4.w);
#pragma unroll
  for (int off = 32; off >= 1; off >>= 1) sumC += __shfl_xor(sumC, off, 64);

  float ab0a = 0.f, ab0b = 0.f, ab1a = 0.f, ab1b = 0.f;
#pragma unroll 8
  for (int u = 0; u < 64; ++u) {
    float4 c = *(const float4*)&Cs[wu][u * 4];   // uniform addr -> broadcast
    ab0a += fabsf(av0 + c.x); ab0b += fabsf(av0 + c.y);
    ab0a += fabsf(av0 + c.z); ab0b += fabsf(av0 + c.w);
    ab1a += fabsf(av1 + c.x); ab1b += fabsf(av1 + c.y);
    ab1a += fabsf(av1 + c.z); ab1b += fabsf(av1 + c.w);
  }

  const float mh0 = (256.f * av0 + sumC + (ab0a + ab0b)) * (1.f / 512.f);
  const float mh1 = (256.f * av1 + sumC + (ab1a + ab1b)) * (1.f / 512.f);
  tl[lane][wu] = f2bf(mh0);
  tl[64 + lane][wu] = f2bf(mh1);
  __syncthreads();

  if (tid < 128) {  // row m-local = tid: 8 bf16 = 16B coalesced store
    *(uint4*)&mhb[(size_t)(b * 256 + r0 + tid) * NH + h0] =
        *(const uint4*)&tl[tid][0];
  }
}

// ---------------------------------------------------------------------------
// k2b: out[m][d] = mh[m,:]@W2[:,d] + b2[d] + x[m][d].  MFMA: A=mhb m-rows,
// B=W2T d-rows -> D[row=m][col=d], coalesced stores. Wave = one 16x16 tile.
// Grid (256 m-tiles, 4 d-groups) x 256 thr = 4096 waves = 16/CU.
// ---------------------------------------------------------------------------
__global__ __launch_bounds__(256) void k2b_mfma(
    const unsigned short* __restrict__ mhb, const unsigned short* __restrict__ W2T,
    const float* __restrict__ b2, const float* __restrict__ x,
    float* __restrict__ out)
{
  const int tid = threadIdx.x, lane = tid & 63, wu = tid >> 6;
  const int m0 = blockIdx.x * 16;
  const int d0 = (blockIdx.y * 4 + wu) * 16;
  const int fr = lane & 15, fq = lane >> 4;

  const unsigned short* apm = mhb + (size_t)(m0 + fr) * NH + fq * 8;
  const unsigned short* bpw = W2T + (size_t)(d0 + fr) * NH + fq * 8;

  f32x4 acc = {0.f, 0.f, 0.f, 0.f};
#pragma unroll
  for (int c = 0; c < 4; ++c) {
    bf16x8 a = *(const bf16x8*)(apm + c * 32);
    bf16x8 bb = *(const bf16x8*)(bpw + c * 32);
    acc = __builtin_amdgcn_mfma_f32_16x16x32_bf16(a, bb, acc, 0, 0, 0);
  }

  const float bv = b2[d0 + fr];
#pragma unroll
  for (int g = 0; g < 4; ++g) {
    const int m = m0 + fq * 4 + g;
    const size_t o = (size_t)m * ND + d0 + fr;
    out[o] = acc[g] + bv + x[o];
  }
}

extern "C" void kernel_launch(void* const* d_in, const int* in_sizes, int n_in,
                              void* d_out, int out_size, void* d_ws, size_t ws_size,
                              hipStream_t stream) {
  const float* x  = (const float*)d_in[0];
  const float* W1 = (const float*)d_in[1];
  const float* b1 = (const float*)d_in[2];
  const float* W2 = (const float*)d_in[3];
  const float* b2 = (const float*)d_in[4];
  float* out = (float*)d_out;

  char* ws = (char*)d_ws;
  float* GT = (float*)ws;                                    // 4 MB
  unsigned short* mhb = (unsigned short*)(ws + (5u << 20));  // 1 MB
  unsigned short* W1T = (unsigned short*)(ws + (7u << 20));  // 128 KB
  unsigned short* W2T = (unsigned short*)(ws + (7u << 20) + (256u << 10));

  kCast<<<384, 256, 0, stream>>>(W1, W2, W1T, W2T);
  k1_mfma<<<dim3(128, 4), 256, 0, stream>>>(x, W1T, b1, GT);
  k2a_pair<<<dim3(16, 2, 16), 512, 0, stream>>>(GT, mhb);
  k2b_mfma<<<dim3(256, 4), 256, 0, stream>>>(mhb, W2T, b2, x, out);
}

// Round 6
// 26.368 us; speedup vs baseline: 2.0471x; 1.2566x over previous
//
#include <hip/hip_runtime.h>

#define NM 4096   // B*K rows
#define NKI 256   // inner k of GEMM1 (= D)
#define NH 128
#define ND 256

typedef __attribute__((ext_vector_type(8))) short bf16x8;
typedef __attribute__((ext_vector_type(4))) float f32x4;

__device__ __forceinline__ unsigned short f2bf(float f) {
  unsigned u = __float_as_uint(f);
  u += 0x7FFFu + ((u >> 16) & 1u);   // RNE
  return (unsigned short)(u >> 16);
}

// ---------------------------------------------------------------------------
// k1: GT[n][m] f32; rows n<128: (x@W1a)^T ; n>=128: (x@W1b+b1)^T.
// MFMA 16x16x32 bf16. A-frags gather-cast DIRECTLY from native W1 (f32,
// L2-hot, 4x64B segments per load instr) — no pre-transposed W1T, no kCast.
// B (x tile) cast to bf16 in swizzled LDS. Block 256 thr: 32 m x 64 n.
// Grid (128 m-tiles, 4 n-groups) = 512 blocks, 2/CU, 8 waves/CU.
// ---------------------------------------------------------------------------
__global__ __launch_bounds__(256) void k1_mfma(
    const float* __restrict__ x, const float* __restrict__ W1,
    const float* __restrict__ b1, float* __restrict__ GT)
{
  __shared__ unsigned short xs[32 * 256];  // [m][k] bf16, 8B-unit XOR swizzle

  const int tid = threadIdx.x, lane = tid & 63, wu = tid >> 6;  // wu 0..3
  const int m0 = blockIdx.x * 32;
  const int n0 = blockIdx.y * 64;
  const int fr = lane & 15, fq = lane >> 4;

  // stage x tile [32 m][256 k] -> bf16 LDS; 8B unit u, phys = u^((row&7)<<1)
#pragma unroll
  for (int r = 0; r < 8; ++r) {
    int idx = r * 256 + tid;
    int row = idx >> 6, u = idx & 63;
    float4 v = *(const float4*)&x[(size_t)(m0 + row) * NKI + u * 4];
    ushort4 hv = make_ushort4(f2bf(v.x), f2bf(v.y), f2bf(v.z), f2bf(v.w));
    int pu = u ^ ((row & 7) << 1);
    *(ushort4*)&xs[row * 256 + pu * 4] = hv;
  }

  // A-frags: afr[c][j] = W1T[nrow][c*32 + fq*8 + j] gathered from native W1:
  //   n<128 -> W1[k*128+n] ; n>=128 -> W1[(256+k)*128 + (n-128)]
  const int isC = (n0 >= 128);
  const int ncol = (n0 & 127) + wu * 16 + fr;  // column within the half
  const float* __restrict__ wp = W1 + (size_t)(isC ? 256 : 0) * NH + ncol;
  bf16x8 afr[8];
#pragma unroll
  for (int c = 0; c < 8; ++c) {
    union { bf16x8 v; unsigned short s[8]; } t;
#pragma unroll
    for (int j = 0; j < 8; ++j)
      t.s[j] = f2bf(wp[(size_t)(c * 32 + fq * 8 + j) * NH]);
    afr[c] = t.v;
  }
  __syncthreads();

#pragma unroll
  for (int ms = 0; ms < 2; ++ms) {
    f32x4 acc = {0.f, 0.f, 0.f, 0.f};
    const int mrow = ms * 16 + fr;
    const int xsw = (mrow & 7) << 1;
#pragma unroll
    for (int c = 0; c < 8; ++c) {
      int pu = (c * 8 + fq * 2) ^ xsw;
      bf16x8 bfr = *(const bf16x8*)&xs[mrow * 256 + pu * 4];
      acc = __builtin_amdgcn_mfma_f32_16x16x32_bf16(afr[c], bfr, acc, 0, 0, 0);
    }
    const int nb = n0 + wu * 16 + fq * 4;
    const int m = m0 + ms * 16 + fr;
#pragma unroll
    for (int g = 0; g < 4; ++g) {
      float v = acc[g];
      const int nn = nb + g;
      if (nn >= 128) v += b1[nn - 128];
      GT[(size_t)nn * NM + m] = v;
    }
  }
}

// ---------------------------------------------------------------------------
// k2a: mh[m,h] = (256*a + sumC + sum_k2 |a+c|)/512  (exact relu-sum identity)
// R=4 rows/thread: halves LDS-pipe reads vs R=2 -> VALU-bound (~3.4 us floor).
// Block 512 thr = 8 waves = 8 h, covers full batch row-block (256 m).
// c-row read as broadcast ds_read_b128 (uniform addr). Grid (16 b, 16 hc)
// = 256 blocks, 1/CU, 8 waves/CU; 32 indep VALU per ds_read hides latency.
// ---------------------------------------------------------------------------
__global__ __launch_bounds__(512) void k2a_pair(
    const float* __restrict__ GT, unsigned short* __restrict__ mhb)
{
  __shared__ float Cs[8][256];
  __shared__ unsigned short tl[256][8];

  const int tid = threadIdx.x, lane = tid & 63, wu = tid >> 6;  // wu 0..7
  const int b = blockIdx.x, hc = blockIdx.y;
  const int h0 = hc * 8;

  // stage 8 c-rows (8KB): 512 threads x 1 float4, coalesced
  {
    int j = tid >> 6, c4 = tid & 63;
    *(float4*)&Cs[j][c4 * 4] =
        *(const float4*)&GT[(size_t)(128 + h0 + j) * NM + b * 256 + c4 * 4];
  }
  const int h = h0 + wu;
  const float* __restrict__ arow = GT + (size_t)h * NM + b * 256;
  const float av0 = arow[lane];
  const float av1 = arow[64 + lane];
  const float av2 = arow[128 + lane];
  const float av3 = arow[192 + lane];
  __syncthreads();

  // sumC for this h: 4 floats/lane + butterfly
  float4 s4 = *(const float4*)&Cs[wu][lane * 4];
  float sumC = (s4.x + s4.y) + (s4.z + s4.w);
#pragma unroll
  for (int off = 32; off >= 1; off >>= 1) sumC += __shfl_xor(sumC, off, 64);

  float ab0a = 0.f, ab0b = 0.f, ab1a = 0.f, ab1b = 0.f;
  float ab2a = 0.f, ab2b = 0.f, ab3a = 0.f, ab3b = 0.f;
#pragma unroll 8
  for (int u = 0; u < 64; ++u) {
    float4 c = *(const float4*)&Cs[wu][u * 4];   // uniform addr -> broadcast
    ab0a += fabsf(av0 + c.x); ab0b += fabsf(av0 + c.y);
    ab0a += fabsf(av0 + c.z); ab0b += fabsf(av0 + c.w);
    ab1a += fabsf(av1 + c.x); ab1b += fabsf(av1 + c.y);
    ab1a += fabsf(av1 + c.z); ab1b += fabsf(av1 + c.w);
    ab2a += fabsf(av2 + c.x); ab2b += fabsf(av2 + c.y);
    ab2a += fabsf(av2 + c.z); ab2b += fabsf(av2 + c.w);
    ab3a += fabsf(av3 + c.x); ab3b += fabsf(av3 + c.y);
    ab3a += fabsf(av3 + c.z); ab3b += fabsf(av3 + c.w);
  }

  tl[lane][wu]       = f2bf((256.f * av0 + sumC + (ab0a + ab0b)) * (1.f / 512.f));
  tl[64 + lane][wu]  = f2bf((256.f * av1 + sumC + (ab1a + ab1b)) * (1.f / 512.f));
  tl[128 + lane][wu] = f2bf((256.f * av2 + sumC + (ab2a + ab2b)) * (1.f / 512.f));
  tl[192 + lane][wu] = f2bf((256.f * av3 + sumC + (ab3a + ab3b)) * (1.f / 512.f));
  __syncthreads();

  if (tid < 256) {  // row m-local = tid: 8 bf16 = 16B coalesced store
    *(uint4*)&mhb[(size_t)(b * 256 + tid) * NH + h0] =
        *(const uint4*)&tl[tid][0];
  }
}

// ---------------------------------------------------------------------------
// k2b: out[m][d] = mh[m,:]@W2[:,d] + b2[d] + x[m][d].  A = mhb m-rows (bf16),
// B gather-cast DIRECTLY from native W2 (f32, L2-hot) — no W2T. Wave = 32 m
// x 16 d (2 MFMA tiles, shared B-frags). Grid (128 m-tiles, 4 d-groups) =
// 512 blocks x 4 waves = 8 waves/CU.
// ---------------------------------------------------------------------------
__global__ __launch_bounds__(256) void k2b_mfma(
    const unsigned short* __restrict__ mhb, const float* __restrict__ W2,
    const float* __restrict__ b2, const float* __restrict__ x,
    float* __restrict__ out)
{
  const int tid = threadIdx.x, lane = tid & 63, wu = tid >> 6;
  const int m0 = blockIdx.x * 32;
  const int d0 = (blockIdx.y * 4 + wu) * 16;
  const int fr = lane & 15, fq = lane >> 4;

  // B-frags: bfr[c][j] = W2T[d0+fr][c*32+fq*8+j] = W2[(c*32+fq*8+j)*256 + d0+fr]
  const float* __restrict__ w2p = W2 + d0 + fr;
  bf16x8 bfr[4];
#pragma unroll
  for (int c = 0; c < 4; ++c) {
    union { bf16x8 v; unsigned short s[8]; } t;
#pragma unroll
    for (int j = 0; j < 8; ++j)
      t.s[j] = f2bf(w2p[(size_t)(c * 32 + fq * 8 + j) * ND]);
    bfr[c] = t.v;
  }

  const float bv = b2[d0 + fr];
#pragma unroll
  for (int ms = 0; ms < 2; ++ms) {
    const unsigned short* apm = mhb + (size_t)(m0 + ms * 16 + fr) * NH + fq * 8;
    f32x4 acc = {0.f, 0.f, 0.f, 0.f};
#pragma unroll
    for (int c = 0; c < 4; ++c) {
      bf16x8 a = *(const bf16x8*)(apm + c * 32);
      acc = __builtin_amdgcn_mfma_f32_16x16x32_bf16(a, bfr[c], acc, 0, 0, 0);
    }
#pragma unroll
    for (int g = 0; g < 4; ++g) {
      const int m = m0 + ms * 16 + fq * 4 + g;
      const size_t o = (size_t)m * ND + d0 + fr;
      out[o] = acc[g] + bv + x[o];
    }
  }
}

extern "C" void kernel_launch(void* const* d_in, const int* in_sizes, int n_in,
                              void* d_out, int out_size, void* d_ws, size_t ws_size,
                              hipStream_t stream) {
  const float* x  = (const float*)d_in[0];
  const float* W1 = (const float*)d_in[1];
  const float* b1 = (const float*)d_in[2];
  const float* W2 = (const float*)d_in[3];
  const float* b2 = (const float*)d_in[4];
  float* out = (float*)d_out;

  char* ws = (char*)d_ws;
  float* GT = (float*)ws;                                    // 4 MB
  unsigned short* mhb = (unsigned short*)(ws + (4u << 20));  // 1 MB

  k1_mfma<<<dim3(128, 4), 256, 0, stream>>>(x, W1, b1, GT);
  k2a_pair<<<dim3(16, 16), 512, 0, stream>>>(GT, mhb);
  k2b_mfma<<<dim3(128, 4), 256, 0, stream>>>(mhb, W2, b2, x, out);
}

// Round 7
// 25.245 us; speedup vs baseline: 2.1381x; 1.0445x over previous
//
#include <hip/hip_runtime.h>

#define NM 4096   // B*K rows
#define NH 128
#define ND 256
#define STR 260   // padded f32 row stride for As/Cs (16B-aligned, bank-spread)

typedef __attribute__((ext_vector_type(8))) short bf16x8;
typedef __attribute__((ext_vector_type(4))) float f32x4;

__device__ __forceinline__ unsigned short f2bf(float f) {
  unsigned u = __float_as_uint(f);
  u += 0x7FFFu + ((u >> 16) & 1u);   // RNE
  return (unsigned short)(u >> 16);
}

// ---------------------------------------------------------------------------
// kA: fused GEMM1-slice + pairwise-mean.  Block (b, hc) owns batch b and
// h-range [h0, h0+8): computes a[·,h] and c[·,h] columns itself (M=16 n-cols,
// N=256 m, K=256 — tiles GEMM1 exactly once across the grid), then
//   mh[m,h] = (256*a + sumC + sum_k2 |a+c|)/512   (exact relu-sum identity).
// x[b] staged once in swizzled bf16 LDS (128 KB); W1 cols gather-cast to
// A-frags (round-6-validated pattern); MFMA D[row=n][col=m] redistributed
// through LDS As/Cs; R=4 broadcast-pairwise loop (round-6-validated).
// Grid (16 b, 16 hc) = 256 blocks, 512 thr, 1 block/CU (144 KB LDS).
// ---------------------------------------------------------------------------
__global__ __launch_bounds__(512) void kA(
    const float* __restrict__ x, const float* __restrict__ W1,
    const float* __restrict__ b1, unsigned short* __restrict__ mhb)
{
  __shared__ __align__(16) unsigned char smem[131072 + 2 * 8320];
  unsigned short* xs = (unsigned short*)smem;          // [256 m][256 k] bf16, swizzled
  float* As = (float*)(smem + 131072);                 // [8 h'][STR] a-values
  float* Cs = (float*)(smem + 131072 + 8320);          // [8 h'][STR] c-values (+b1)

  const int tid = threadIdx.x, lane = tid & 63, wu = tid >> 6;  // wu 0..7
  const int b = blockIdx.x, hc = blockIdx.y;
  const int h0 = hc * 8;
  const int fr = lane & 15, fq = lane >> 4;

  // A-frags: 16 n-cols; n<8 -> W1a col h0+n, n>=8 -> W1b col h0+n-8.
  // afr[c].s[j] = W1col[n=fr][k = c*32 + fq*8 + j]  (validated gather-cast)
  const float* __restrict__ wp =
      W1 + (size_t)((fr >= 8) ? 256 : 0) * NH + h0 + (fr & 7);
  bf16x8 afr[8];
#pragma unroll
  for (int c = 0; c < 8; ++c) {
    union { bf16x8 v; unsigned short s[8]; } t;
#pragma unroll
    for (int j = 0; j < 8; ++j)
      t.s[j] = f2bf(wp[(size_t)(c * 32 + fq * 8 + j) * NH]);
    afr[c] = t.v;
  }

  // stage x[b] (256x256 f32) -> bf16 LDS; 8B unit u, phys = u ^ ((row&7)<<1)
#pragma unroll 8
  for (int i = 0; i < 32; ++i) {
    const int idx = i * 512 + tid;
    const int row = idx >> 6, u = idx & 63;
    float4 v = *(const float4*)&x[(size_t)(b * 256 + row) * 256 + u * 4];
    ushort4 hv = make_ushort4(f2bf(v.x), f2bf(v.y), f2bf(v.z), f2bf(v.w));
    *(ushort4*)&xs[row * 256 + (u ^ ((row & 7) << 1)) * 4] = hv;
  }
  __syncthreads();

  float b1v[4] = {0.f, 0.f, 0.f, 0.f};
  if (fq >= 2) {
#pragma unroll
    for (int g = 0; g < 4; ++g) b1v[g] = b1[h0 + (fq - 2) * 4 + g];
  }

  // MFMA: wave handles m-tiles {2wu, 2wu+1}; D row = n (A's dim), col = m.
#pragma unroll
  for (int ts = 0; ts < 2; ++ts) {
    const int mrow = (wu * 2 + ts) * 16 + fr;
    const int swz = (mrow & 7) << 1;
    f32x4 acc = {0.f, 0.f, 0.f, 0.f};
#pragma unroll
    for (int c = 0; c < 8; ++c) {
      const int pu = (c * 8 + fq * 2) ^ swz;
      bf16x8 bfr = *(const bf16x8*)&xs[mrow * 256 + pu * 4];
      acc = __builtin_amdgcn_mfma_f32_16x16x32_bf16(afr[c], bfr, acc, 0, 0, 0);
    }
    // lane holds m = mrow, n = fq*4+g: n<8 -> As[n][m], n>=8 -> Cs[n-8][m]+b1
    if (fq < 2) {
#pragma unroll
      for (int g = 0; g < 4; ++g) As[(fq * 4 + g) * STR + mrow] = acc[g];
    } else {
#pragma unroll
      for (int g = 0; g < 4; ++g)
        Cs[((fq - 2) * 4 + g) * STR + mrow] = acc[g] + b1v[g];
    }
  }
  __syncthreads();

  // pairwise: wave wu owns h' = wu; R=4 m-rows/thread; Cs read as broadcast.
  const float* __restrict__ Arow = As + wu * STR;
  const float* __restrict__ Crow = Cs + wu * STR;
  const float a0 = Arow[lane];
  const float a1 = Arow[64 + lane];
  const float a2 = Arow[128 + lane];
  const float a3 = Arow[192 + lane];

  float4 s4 = *(const float4*)&Crow[lane * 4];
  float sumC = (s4.x + s4.y) + (s4.z + s4.w);
#pragma unroll
  for (int off = 32; off >= 1; off >>= 1) sumC += __shfl_xor(sumC, off, 64);

  float ab0a = 0.f, ab0b = 0.f, ab1a = 0.f, ab1b = 0.f;
  float ab2a = 0.f, ab2b = 0.f, ab3a = 0.f, ab3b = 0.f;
#pragma unroll 8
  for (int u = 0; u < 64; ++u) {
    float4 c = *(const float4*)&Crow[u * 4];   // uniform addr -> broadcast
    ab0a += fabsf(a0 + c.x); ab0b += fabsf(a0 + c.y);
    ab0a += fabsf(a0 + c.z); ab0b += fabsf(a0 + c.w);
    ab1a += fabsf(a1 + c.x); ab1b += fabsf(a1 + c.y);
    ab1a += fabsf(a1 + c.z); ab1b += fabsf(a1 + c.w);
    ab2a += fabsf(a2 + c.x); ab2b += fabsf(a2 + c.y);
    ab2a += fabsf(a2 + c.z); ab2b += fabsf(a2 + c.w);
    ab3a += fabsf(a3 + c.x); ab3b += fabsf(a3 + c.y);
    ab3a += fabsf(a3 + c.z); ab3b += fabsf(a3 + c.w);
  }

  const float mh0 = (256.f * a0 + sumC + (ab0a + ab0b)) * (1.f / 512.f);
  const float mh1 = (256.f * a1 + sumC + (ab1a + ab1b)) * (1.f / 512.f);
  const float mh2 = (256.f * a2 + sumC + (ab2a + ab2b)) * (1.f / 512.f);
  const float mh3 = (256.f * a3 + sumC + (ab3a + ab3b)) * (1.f / 512.f);
  __syncthreads();          // all As/Cs reads complete

  // reuse As as mh staging [h'][m] (f32, conflict-free column writes)
  As[wu * STR + lane]       = mh0;
  As[wu * STR + 64 + lane]  = mh1;
  As[wu * STR + 128 + lane] = mh2;
  As[wu * STR + 192 + lane] = mh3;
  __syncthreads();

  if (tid < 256) {  // row m = tid: gather 8 h', pack, 16B coalesced store
    union { uint4 v; unsigned short s[8]; } o;
#pragma unroll
    for (int j = 0; j < 8; ++j) o.s[j] = f2bf(As[j * STR + tid]);
    *(uint4*)&mhb[(size_t)(b * 256 + tid) * NH + h0] = o.v;
  }
}

// ---------------------------------------------------------------------------
// kB: out[m][d] = mh[m,:]@W2[:,d] + b2[d] + x[m][d].  A = mhb m-rows (bf16),
// B gather-cast from native W2 (f32, L2-hot). Wave = 32 m x 16 d.
// Grid (128 m-tiles, 4 d-groups) = 512 blocks x 4 waves = 8 waves/CU.
// (unchanged, round-6-validated)
// ---------------------------------------------------------------------------
__global__ __launch_bounds__(256) void kB_mfma(
    const unsigned short* __restrict__ mhb, const float* __restrict__ W2,
    const float* __restrict__ b2, const float* __restrict__ x,
    float* __restrict__ out)
{
  const int tid = threadIdx.x, lane = tid & 63, wu = tid >> 6;
  const int m0 = blockIdx.x * 32;
  const int d0 = (blockIdx.y * 4 + wu) * 16;
  const int fr = lane & 15, fq = lane >> 4;

  const float* __restrict__ w2p = W2 + d0 + fr;
  bf16x8 bfr[4];
#pragma unroll
  for (int c = 0; c < 4; ++c) {
    union { bf16x8 v; unsigned short s[8]; } t;
#pragma unroll
    for (int j = 0; j < 8; ++j)
      t.s[j] = f2bf(w2p[(size_t)(c * 32 + fq * 8 + j) * ND]);
    bfr[c] = t.v;
  }

  const float bv = b2[d0 + fr];
#pragma unroll
  for (int ms = 0; ms < 2; ++ms) {
    const unsigned short* apm = mhb + (size_t)(m0 + ms * 16 + fr) * NH + fq * 8;
    f32x4 acc = {0.f, 0.f, 0.f, 0.f};
#pragma unroll
    for (int c = 0; c < 4; ++c) {
      bf16x8 a = *(const bf16x8*)(apm + c * 32);
      acc = __builtin_amdgcn_mfma_f32_16x16x32_bf16(a, bfr[c], acc, 0, 0, 0);
    }
#pragma unroll
    for (int g = 0; g < 4; ++g) {
      const int m = m0 + ms * 16 + fq * 4 + g;
      const size_t o = (size_t)m * ND + d0 + fr;
      out[o] = acc[g] + bv + x[o];
    }
  }
}

extern "C" void kernel_launch(void* const* d_in, const int* in_sizes, int n_in,
                              void* d_out, int out_size, void* d_ws, size_t ws_size,
                              hipStream_t stream) {
  const float* x  = (const float*)d_in[0];
  const float* W1 = (const float*)d_in[1];
  const float* b1 = (const float*)d_in[2];
  const float* W2 = (const float*)d_in[3];
  const float* b2 = (const float*)d_in[4];
  float* out = (float*)d_out;

  unsigned short* mhb = (unsigned short*)d_ws;   // 4096 x 128 bf16 = 1 MB

  kA<<<dim3(16, 16), 512, 0, stream>>>(x, W1, b1, mhb);
  kB_mfma<<<dim3(128, 4), 256, 0, stream>>>(mhb, W2, b2, x, out);
}